// Round 19
// baseline (132.436 us; speedup 1.0000x reference)
//
#include <hip/hip_runtime.h>
#include <hip/hip_bf16.h>

typedef __hip_bfloat16 bf16t;
typedef _Float16 half_t;
typedef __attribute__((ext_vector_type(2))) _Float16 half2v;
typedef __attribute__((ext_vector_type(8))) _Float16 half8v;
typedef __attribute__((ext_vector_type(4))) float f32x4;
typedef unsigned int uint32;

#define BB   32
#define NC   60
#define NROW 2880
#define NB3  1440            // k3 MLP blocks (2 instances each)
#define NFOLDB 1600
#define EPSF 1e-5f
#define ALPHA 0.2f
#define DEG  4

// ws layout (bytes). Slow path <=869376 (proven). Fast path <=44450816 (proven).
#define WS_M_OFF    256
#define WS_PW_OFF   4096
#define WS_W3BF_OFF 28672
#define WS_W2BF_OFF 77824
#define WS_W1BF_OFF 88064
#define WS_WCP_OFF  101376
#define WS_WCPF_OFF 869376
#define WS_PART_OFF 1688576
#define WS_GH3_OFF  7586816
#define WS_NEED     44450816ULL

// pw float offsets
#define P_W1  0
#define P_B1  1152
#define P_G1  1200
#define P_BE1 1248
#define P_W2  1296
#define P_B2  4752
#define P_G2  4824
#define P_BE2 4896
#define P_B3  4968
#define P_G3  5224
#define P_BE3 5480
#define P_BC  5736
#define P_TOT 5796
#define R_W3E (P_TOT+24576)
#define R_W2E (R_W3E+5120)
#define R_W1E (R_W2E+1536)
#define PREP_K1B 145            // ceil(R_W1E/256); block 145 builds M

// k3 LDS byte offsets (37888 B; R12-proven)
#define LB_H3L 0        // f16 [25][256] raw h3 rows 0..24
#define LB_A1  12800    // f16 [64][72]
#define LB_CS  12800    // float[240] overlay on A1 (fused classifier phase only)
#define LB_A2  22016    // f16 [64][104]
#define LB_H3H 22016    // f16 [25][256] raw h3 rows 25..49, overlays A2
#define LB_STW 35328    // float[512]
#define LB_ST2 37376    // float[128]
#define LDS_FTOT 9472   // 37888 B

__device__ __forceinline__ float ldin(const void* p, int i, int isbf){
  return isbf ? __bfloat162float(((const bf16t*)p)[i]) : ((const float*)p)[i];
}
__device__ __forceinline__ void stout(void* p, int i, int isbf, float v){
  if(isbf) ((bf16t*)p)[i] = __float2bfloat16(v);
  else     ((float*)p)[i] = v;
}
__device__ __forceinline__ half2v u2h2(uint32 u){
  half2v h; __builtin_memcpy(&h,&u,4); return h;
}
__device__ __forceinline__ uint32 pk2u(float a, float b){
  auto r = __builtin_amdgcn_cvt_pkrtz(a, b);
  uint32 u; __builtin_memcpy(&u,&r,4); return u;
}

// ======================= FAST PATH =======================

// ---- k_prep: dtype-detect + param packs; block 145 builds M -> ws
__global__ void k_prep(const void* W1,const void* b1,const void* g1,const void* be1,
                       const void* W2,const void* b2,const void* g2,const void* be2,
                       const void* W3,const void* b3,const void* g3,const void* be3,
                       const void* bc, const void* x, const void* adj,
                       int* flagp, float* pw, float* M,
                       half_t* W3bf, half_t* W2bf, half_t* W1bf){
  __shared__ float A[625], Pp[625], Q[625], Ss[625];
  __shared__ int cnt;
  int t = threadIdx.x, bid = blockIdx.x;
  if(t==0) cnt = 0;
  __syncthreads();
  {
    const unsigned short* xb = (const unsigned short*)x;
    unsigned short u = xb[2*t];
    int e = (u>>7)&0xFF;
    if(e>=100 && e<=141) atomicAdd(&cnt,1);
  }
  __syncthreads();
  int isbf = (cnt>=160) ? 1 : 0;
  if(bid==0 && t==0) flagp[0] = isbf;

  if(bid < PREP_K1B){
    int o = bid*256 + t;
    if(o < P_TOT){
      const void* src; int loc;
      if      (o < P_B1 ) { src=W1;  loc=o;        }
      else if (o < P_G1 ) { src=b1;  loc=o-P_B1;   }
      else if (o < P_BE1) { src=g1;  loc=o-P_G1;   }
      else if (o < P_W2 ) { src=be1; loc=o-P_BE1;  }
      else if (o < P_B2 ) { src=W2;  loc=o-P_W2;   }
      else if (o < P_G2 ) { src=b2;  loc=o-P_B2;   }
      else if (o < P_BE2) { src=g2;  loc=o-P_G2;   }
      else if (o < P_B3 ) { src=be2; loc=o-P_BE2;  }
      else if (o < P_G3 ) { src=b3;  loc=o-P_B3;   }
      else if (o < P_BE3) { src=g3;  loc=o-P_G3;   }
      else if (o < P_BC ) { src=be3; loc=o-P_BE3;  }
      else                { src=bc;  loc=o-P_BC;   }
      pw[o] = ldin(src, loc, isbf);
    } else if(o < R_W3E){
      int o2 = o - P_TOT;
      int ct = o2/1536, rem = o2 - ct*1536;
      int kt = rem/512, rem2 = rem - kt*512;
      int l = rem2>>3, j = rem2&7;
      int k = kt*32 + ((l>>4)<<3) + j;
      int col = (ct<<4) + (l&15);
      float v = (k<72) ? ldin(W3, k*256+col, isbf) : 0.f;
      W3bf[o2] = (half_t)v;
    } else if(o < R_W2E){
      int o2 = o - R_W3E;
      int ct = o2/1024, rem = o2 - ct*1024;
      int kt = rem/512, rem2 = rem - kt*512;
      int l = rem2>>3, j = rem2&7;
      int k = kt*32 + ((l>>4)<<3) + j;
      int col = (ct<<4) + (l&15);
      float v = (k<48 && col<72) ? ldin(W2, k*72+col, isbf) : 0.f;
      W2bf[o2] = (half_t)v;
    } else if(o < R_W1E){
      int o2 = o - R_W2E;
      int ct = o2/512, rem2 = o2 - ct*512;
      int l = rem2>>3, j = rem2&7;
      int k = ((l>>4)<<3) + j;
      int col = (ct<<4) + (l&15);
      float v = (k<24) ? ldin(W1, k*48+col, isbf) : 0.f;
      W1bf[o2] = (half_t)v;
    }
  } else {
    for(int i=t;i<625;i+=256){ float a=ldin(adj,i,isbf); A[i]=a; Pp[i]=a; Ss[i]=a; }
    __syncthreads();
    for(int d=1; d<DEG; ++d){
      for(int o=t;o<625;o+=256){
        int i=o/25, j=o%25; float acc=0.f;
        for(int k=0;k<25;k++) acc += A[i*25+k]*Pp[k*25+j];
        Q[o]=acc;
      }
      __syncthreads();
      for(int o=t;o<625;o+=256){ Pp[o]=Q[o]; Ss[o]+=Q[o]; }
      __syncthreads();
    }
    const float coef = (1.0f-ALPHA)/(float)DEG;
    for(int o=t;o<625;o+=256){
      int i=o/25, j=o%25;
      M[o] = (i==j ? ALPHA : 0.0f) + coef*Ss[o];
    }
  }
}

// ---- k3c: blocks [0,1440) = MLP pipeline x2 instances; blocks [1440,3040) = Wcpf fold
__global__ __launch_bounds__(256,4) void k3_fast(const void* x, const float* pw,
                                              const half_t* W3bf_, const half_t* W2bf_,
                                              const half_t* W1bf_,
                                              const float* M, const void* Wc,
                                              half_t* Wcpf,
                                              const int* flagp, uint32* gH3d){
  __shared__ float sm[LDS_FTOT];
  char* smb = (char*)sm;
  half_t* H3L = (half_t*)(smb + LB_H3L);
  half_t* H3H = (half_t*)(smb + LB_H3H);   // overlays A2
  half_t* A1h = (half_t*)(smb + LB_A1);
  half_t* A2h = (half_t*)(smb + LB_A2);
  float*  stw = (float*)(smb + LB_STW);
  float*  st2 = (float*)(smb + LB_ST2);
  uint32* A1w = (uint32*)A1h;
  const unsigned short* W3u = (const unsigned short*)W3bf_;
  const unsigned short* W2u = (const unsigned short*)W2bf_;
  const unsigned short* W1u = (const unsigned short*)W1bf_;

  int t = threadIdx.x, bid = blockIdx.x;
  int isbf = flagp[0];

  if(bid >= NB3){
    // ---- fold body: Wcpf [kst][nt][lane][8] (R12 K-linear pairing); M from ws
    int o = (bid-NB3)*256 + t;   // exact 409600
    int j = o&7, l = (o>>3)&63, nt = (o>>9)&3, kst = o>>11;
    int k = kst*32 + ((l>>4)<<3) + j;
    int c = nt*16 + (l&15);
    float acc = 0.f;
    if(c < 60){
      int jj = k>>8, f = k&255;
      for(int i=0;i<25;i++) acc += M[i*25+jj]*ldin(Wc, (i*256+f)*60 + c, isbf);
    }
    Wcpf[o] = (half_t)(0.5f*acc);
    return;
  }

  int l = t&63, w = t>>6, cb = l&15, g4 = l>>4;
  const float* b1=pw+P_B1;  const float* g1=pw+P_G1;  const float* be1=pw+P_BE1;
  const float* b2=pw+P_B2;  const float* g2=pw+P_G2;  const float* be2=pw+P_BE2;
  const float* b3=pw+P_B3;  const float* g3=pw+P_G3;  const float* be3=pw+P_BE3;

  // instance-invariant scalars (hoisted across both instances)
  float b1v[3], g1v[3], be1v[3];
  #pragma unroll
  for(int ct=0;ct<3;ct++){
    int col = ct*16 + cb;
    b1v[ct]=b1[col]; g1v[ct]=g1[col]; be1v[ct]=be1[col];
  }
  float b2v[5], g2v[5], be2v[5];
  #pragma unroll
  for(int ct=0;ct<5;ct++){
    int col = ct*16 + cb;
    b2v[ct]  = (col<72) ? b2[col]  : 0.f;
    g2v[ct]  = (col<72) ? g2[col]  : 0.f;
    be2v[ct] = (col<72) ? be2[col] : 0.f;
  }
  float b3v[4];
  #pragma unroll
  for(int nt=0;nt<4;nt++) b3v[nt] = b3[w*64 + nt*16 + cb];

  // phase 0: zero A1 col-pad 48..63 once (LN1 never writes cols>=48)
  for(int o=t;o<512;o+=256){ int r=o>>3, dc=24+(o&7); A1w[r*36+dc]=0; }

  #pragma unroll 1
  for(int q=0;q<2;q++){
    int inst = bid*2 + q;

    // ---- MFMA1: A direct from global x
    {
      f32x4 acc1[3];
      #pragma unroll
      for(int ct=0;ct<3;ct++){ acc1[ct][0]=b1v[ct]; acc1[ct][1]=b1v[ct]; acc1[ct][2]=b1v[ct]; acc1[ct][3]=b1v[ct]; }
      int row = w*16 + cb;
      half8v a;
      if(g4 < 3 && row < 50){
        int base = inst*1200 + row*24 + g4*8;
        #pragma unroll
        for(int j=0;j<8;j++) a[j] = (half_t)ldin(x, base+j, isbf);
      } else {
        #pragma unroll
        for(int j=0;j<8;j++) a[j] = (half_t)0.f;
      }
      #pragma unroll
      for(int ct=0;ct<3;ct++){
        half8v b = *(const half8v*)(W1u + (ct*64 + l)*8);
        acc1[ct] = __builtin_amdgcn_mfma_f32_16x16x32_f16(a, b, acc1[ct], 0,0,0);
      }
      __syncthreads();   // S1: q==0: pad zeros visible; q==1: prev-inst H3H reads done
      #pragma unroll
      for(int r=0;r<4;r++){
        float s1 = acc1[0][r]+acc1[1][r]+acc1[2][r];
        float s2 = acc1[0][r]*acc1[0][r]+acc1[1][r]*acc1[1][r]+acc1[2][r]*acc1[2][r];
        #pragma unroll
        for(int d=1;d<16;d<<=1){ s1+=__shfl_xor(s1,d,64); s2+=__shfl_xor(s2,d,64); }
        float m = s1*(1.f/48.f);
        float var = s2*(1.f/48.f)-m*m;
        float rs = rsqrtf(var+EPSF);
        int rw = w*16 + (g4<<2) + r;
        #pragma unroll
        for(int ct=0;ct<3;ct++){
          float val = (acc1[ct][r]-m)*rs*g1v[ct]+be1v[ct];
          A1h[rw*72 + ct*16 + cb] = (half_t)fmaxf(val,0.f);
        }
      }
    }
    // no barrier: A1 rows written/read by same wave

    // ---- MFMA2
    {
      f32x4 acc2[5];
      #pragma unroll
      for(int ct=0;ct<5;ct++){ acc2[ct][0]=b2v[ct]; acc2[ct][1]=b2v[ct]; acc2[ct][2]=b2v[ct]; acc2[ct][3]=b2v[ct]; }
      #pragma unroll
      for(int kt=0;kt<2;kt++){
        half8v a = *(const half8v*)(A1h + (w*16 + cb)*72 + kt*32 + (g4<<3));
        #pragma unroll
        for(int ct=0;ct<5;ct++){
          half8v b = *(const half8v*)(W2u + ((ct*2+kt)*64 + l)*8);
          acc2[ct] = __builtin_amdgcn_mfma_f32_16x16x32_f16(a, b, acc2[ct], 0,0,0);
        }
      }
      int valid4 = (cb<8);
      #pragma unroll
      for(int r=0;r<4;r++){
        float s1 = acc2[0][r]+acc2[1][r]+acc2[2][r]+acc2[3][r] + (valid4?acc2[4][r]:0.f);
        float s2 = acc2[0][r]*acc2[0][r]+acc2[1][r]*acc2[1][r]
                 + acc2[2][r]*acc2[2][r]+acc2[3][r]*acc2[3][r]
                 + (valid4?acc2[4][r]*acc2[4][r]:0.f);
        #pragma unroll
        for(int d=1;d<16;d<<=1){ s1+=__shfl_xor(s1,d,64); s2+=__shfl_xor(s2,d,64); }
        float m = s1*(1.f/72.f);
        float var = s2*(1.f/72.f)-m*m;
        float rs = rsqrtf(var+EPSF);
        int grow = w*16 + (g4<<2) + r;
        #pragma unroll
        for(int ct=0;ct<5;ct++){
          int col = ct*16 + cb;
          if(ct<4 || valid4){
            float val = (acc2[ct][r]-m)*rs*g2v[ct]+be2v[ct];
            A2h[grow*104+col] = (half_t)fmaxf(val,0.f);
          }
        }
      }
      uint32* A2w = (uint32*)A2h;
      for(int o=l;o<192;o+=64){ int rr = w*16 + o/12, dc = 36 + (o - (o/12)*12); A2w[rr*52+dc]=0; }
    }
    __syncthreads();   // S2: A2 complete before all-row MFMA3 reads

    // ---- MFMA3 two M-passes (W3 frags loaded per pass from L2; compiler schedules)
    #pragma unroll 1
    for(int p=0;p<2;p++){
      f32x4 acc[2][4];
      #pragma unroll
      for(int nt=0;nt<4;nt++){
        #pragma unroll
        for(int m2=0;m2<2;m2++){ acc[m2][nt][0]=b3v[nt]; acc[m2][nt][1]=b3v[nt]; acc[m2][nt][2]=b3v[nt]; acc[m2][nt][3]=b3v[nt]; }
      }
      #pragma unroll
      for(int kt=0;kt<3;kt++){
        half8v a[2];
        #pragma unroll
        for(int m2=0;m2<2;m2++)
          a[m2] = *(const half8v*)(A2h + ((p*2+m2)*16+cb)*104 + kt*32 + (g4<<3));
        #pragma unroll
        for(int nt=0;nt<4;nt++){
          half8v b = *(const half8v*)(W3u + (((w*4+nt)*3+kt)*64 + l)*8);
          #pragma unroll
          for(int m2=0;m2<2;m2++)
            acc[m2][nt] = __builtin_amdgcn_mfma_f32_16x16x32_f16(a[m2], b, acc[m2][nt], 0,0,0);
        }
      }
      __syncthreads();   // S3/S4: A2 reads done before H3H-overlay writes
      #pragma unroll
      for(int m2=0;m2<2;m2++){
        #pragma unroll
        for(int r=0;r<4;r++){
          int row = (p*2+m2)*16 + (g4<<2) + r;
          float s1 = acc[m2][0][r]+acc[m2][1][r]+acc[m2][2][r]+acc[m2][3][r];
          float s2 = acc[m2][0][r]*acc[m2][0][r]+acc[m2][1][r]*acc[m2][1][r]
                   + acc[m2][2][r]*acc[m2][2][r]+acc[m2][3][r]*acc[m2][3][r];
          #pragma unroll
          for(int d=1;d<16;d<<=1){ s1+=__shfl_xor(s1,d,64); s2+=__shfl_xor(s2,d,64); }
          if(cb==0){
            stw[row*8 + w*2]   = s1;
            stw[row*8 + w*2+1] = s2;
          }
          if(row<50){
            #pragma unroll
            for(int nt=0;nt<4;nt++){
              int col = w*64 + nt*16 + cb;
              if(row<25) H3L[row*256+col]      = (half_t)acc[m2][nt][r];
              else       H3H[(row-25)*256+col] = (half_t)acc[m2][nt][r];
            }
          }
        }
      }
    }
    __syncthreads();   // S5
    if(t<64){
      float S1 = stw[t*8+0]+stw[t*8+2]+stw[t*8+4]+stw[t*8+6];
      float S2 = stw[t*8+1]+stw[t*8+3]+stw[t*8+5]+stw[t*8+7];
      float m = S1*(1.f/256.f);
      float var = S2*(1.f/256.f)-m*m;
      st2[2*t]=m; st2[2*t+1]=rsqrtf(var+EPSF);
    }
    __syncthreads();   // S6
    // LN3 scale + s-sum -> gH3 (per-thread uint32; R12-proven clean write pattern)
    {
      uint32* H3l32 = (uint32*)H3L;
      uint32* H3h32 = (uint32*)H3H;
      int cp = t & 127, ro = t>>7;
      float ga=g3[2*cp], gb=g3[2*cp+1], ba=be3[2*cp], bb=be3[2*cp+1];
      for(int r=ro; r<25; r+=2){
        uint32 lo = H3l32[r*128+cp], hi = H3h32[r*128+cp];
        float ml=st2[2*r], rl=st2[2*r+1];
        float mh=st2[2*(r+25)], rh=st2[2*(r+25)+1];
        half2v l2=u2h2(lo), h2=u2h2(hi);
        float v0 = ((float)l2[0]-ml)*rl*ga+ba + ((float)h2[0]-mh)*rh*ga+ba;
        float v1 = ((float)l2[1]-ml)*rl*gb+bb + ((float)h2[1]-mh)*rh*gb+bb;
        gH3d[(size_t)inst*3200 + r*128 + cp] = pk2u(v0, v1);
      }
    }
    // next instance's first H3H-region write is after its S1 barrier -> safe
  }
}

// ---- k5: GEMM [2880,6400]@[6400,64p]; grid (45, 8)
__global__ __launch_bounds__(256) void k5_gemm(const half_t* gH3, const half_t* Wcpf,
                                               float* part){
  int bx = blockIdx.x, ky = blockIdx.y;
  int t = threadIdx.x, l = t&63, w = t>>6, cb = l&15, g4 = l>>4;
  const unsigned short* H = (const unsigned short*)gH3;
  const unsigned short* W = (const unsigned short*)Wcpf;
  int base = bx*64 + w*16;
  f32x4 acc[4];
  #pragma unroll
  for(int nt=0;nt<4;nt++){ acc[nt][0]=0.f; acc[nt][1]=0.f; acc[nt][2]=0.f; acc[nt][3]=0.f; }
  int kst0 = ky*25;
  for(int ks=0;ks<25;ks++){
    int kst = kst0 + ks;
    half8v a = *(const half8v*)(H + (size_t)(base+cb)*6400 + kst*32 + (g4<<3));
    #pragma unroll
    for(int nt=0;nt<4;nt++){
      half8v b = *(const half8v*)(W + ((kst*4+nt)*64 + l)*8);
      acc[nt] = __builtin_amdgcn_mfma_f32_16x16x32_f16(a, b, acc[nt], 0,0,0);
    }
  }
  #pragma unroll
  for(int nt=0;nt<4;nt++){
    #pragma unroll
    for(int r=0;r<4;r++){
      int inst = base + (g4<<2) + r;
      part[((size_t)ky*NROW + inst)*64 + nt*16 + cb] = acc[nt][r];
    }
  }
}

// ---- k6_out: fused block_mean (+bias, 8 partials) and pred; grid 32
__global__ void k6_out(const float* part, const float* pw, const int* flagp, void* out){
  __shared__ float bm[5400];
  int b = blockIdx.x, t = threadIdx.x;
  int isbf = flagp[0];
  for(int o=t;o<5400;o+=256){
    int li = o/60, c = o - li*60;
    int inst = b*90 + li;
    float v = pw[P_BC + c];
    #pragma unroll
    for(int ky=0;ky<8;ky++) v += part[((size_t)ky*NROW + inst)*64 + c];
    bm[o] = v;
    stout(out, inst*NC + c, isbf, v);
  }
  __syncthreads();
  if(t<NC){
    float a = 0.f;
    for(int r=0;r<90;r++) a += bm[r*60+t];
    stout(out, NROW*NC + b*NC + t, isbf, a*(1.f/90.f));
  }
}

// ======================= SLOW PATH (fallback, proven) =======================

__global__ void k0_prep(const void* x, const void* adj, int* flagp, float* M){
  __shared__ float A[625], P[625], Q[625], Ss[625];
  __shared__ int cnt, flg;
  int t = threadIdx.x;
  if(t==0) cnt = 0;
  __syncthreads();
  {
    const unsigned short* xb = (const unsigned short*)x;
    unsigned short u = xb[2*t];
    int e = (u>>7)&0xFF;
    if(e>=100 && e<=141) atomicAdd(&cnt,1);
  }
  __syncthreads();
  if(t==0){ flg = (cnt>=160)?1:0; flagp[0]=flg; }
  __syncthreads();
  int isbf = flg;
  for(int i=t;i<625;i+=256){ float a=ldin(adj,i,isbf); A[i]=a; P[i]=a; Ss[i]=a; }
  __syncthreads();
  for(int d=1; d<DEG; ++d){
    for(int o=t;o<625;o+=256){
      int i=o/25, j=o%25; float acc=0.f;
      for(int k=0;k<25;k++) acc += A[i*25+k]*P[k*25+j];
      Q[o]=acc;
    }
    __syncthreads();
    for(int o=t;o<625;o+=256){ P[o]=Q[o]; Ss[o]+=Q[o]; }
    __syncthreads();
  }
  const float coef = (1.0f-ALPHA)/(float)DEG;
  for(int o=t;o<625;o+=256){
    int i=o/25, j=o%25;
    M[o] = (i==j ? ALPHA : 0.0f) + coef*Ss[o];
  }
}

__global__ void k1_all(const void* W1,const void* b1,const void* g1,const void* be1,
                       const void* W2,const void* b2,const void* g2,const void* be2,
                       const void* W3,const void* b3,const void* g3,const void* be3,
                       const void* bc, const int* flagp,
                       float* pw, half_t* W3bf, half_t* W2bf, half_t* W1bf){
  int isbf = flagp[0];
  int o = blockIdx.x*256 + threadIdx.x;
  if(o < P_TOT){
    const void* src; int loc;
    if      (o < P_B1 ) { src=W1;  loc=o;        }
    else if (o < P_G1 ) { src=b1;  loc=o-P_B1;   }
    else if (o < P_BE1) { src=g1;  loc=o-P_G1;   }
    else if (o < P_W2 ) { src=be1; loc=o-P_BE1;  }
    else if (o < P_B2 ) { src=W2;  loc=o-P_W2;   }
    else if (o < P_G2 ) { src=b2;  loc=o-P_B2;   }
    else if (o < P_BE2) { src=g2;  loc=o-P_G2;   }
    else if (o < P_B3 ) { src=be2; loc=o-P_BE2;  }
    else if (o < P_G3 ) { src=b3;  loc=o-P_B3;   }
    else if (o < P_BE3) { src=g3;  loc=o-P_G3;   }
    else if (o < P_BC ) { src=be3; loc=o-P_BE3;  }
    else                { src=bc;  loc=o-P_BC;   }
    pw[o] = ldin(src, loc, isbf);
  } else if(o < R_W3E){
    int o2 = o - P_TOT;
    int ct = o2/1536, rem = o2 - ct*1536;
    int kt = rem/512, rem2 = rem - kt*512;
    int l = rem2>>3, j = rem2&7;
    int k = kt*32 + ((l>>4)<<3) + j;
    int col = (ct<<4) + (l&15);
    float v = (k<72) ? ldin(W3, k*256+col, isbf) : 0.f;
    W3bf[o2] = (half_t)v;
  } else if(o < R_W2E){
    int o2 = o - R_W3E;
    int ct = o2/1024, rem = o2 - ct*1024;
    int kt = rem/512, rem2 = rem - kt*512;
    int l = rem2>>3, j = rem2&7;
    int k = kt*32 + ((l>>4)<<3) + j;
    int col = (ct<<4) + (l&15);
    float v = (k<48 && col<72) ? ldin(W2, k*72+col, isbf) : 0.f;
    W2bf[o2] = (half_t)v;
  } else if(o < R_W1E){
    int o2 = o - R_W2E;
    int ct = o2/512, rem2 = o2 - ct*512;
    int l = rem2>>3, j = rem2&7;
    int k = ((l>>4)<<3) + j;
    int col = (ct<<4) + (l&15);
    float v = (k<24) ? ldin(W1, k*48+col, isbf) : 0.f;
    W1bf[o2] = (half_t)v;
  }
}

__global__ void k2_fold(const void* Wc, const float* M, const int* flagp, half_t* Wcp4){
  int isbf = flagp[0];
  int o = blockIdx.x*256 + threadIdx.x;
  if(o >= 384000) return;
  int grp = o>>4, hw = o&15;
  int kt = grp/15, cg = grp - kt*15;
  int p = hw>>3, cl = (hw>>1)&3, e = hw&1;
  int fl = kt*4 + 2*p + e;
  int j = fl>>8, f = fl&255;
  int c = cg*4 + cl;
  float acc = 0.f;
  for(int i=0;i<25;i++) acc += M[i*25+j]*ldin(Wc, (i*256+f)*60 + c, isbf);
  Wcp4[o] = (half_t)(0.5f*acc);
}

__global__ __launch_bounds__(256,4) void k3_fused(const void* x, const float* pw,
                                              const half_t* W3bf_, const half_t* W2bf_,
                                              const half_t* W1bf_,
                                              const unsigned short* Wcp4,
                                              const int* flagp, void* out){
  __shared__ float sm[LDS_FTOT];
  char* smb = (char*)sm;
  half_t* H3L = (half_t*)(smb + LB_H3L);
  half_t* H3H = (half_t*)(smb + LB_H3H);
  half_t* A1h = (half_t*)(smb + LB_A1);
  half_t* A2h = (half_t*)(smb + LB_A2);
  half_t* XH  = A2h;
  float*  stw = (float*)(smb + LB_STW);
  float*  st2 = (float*)(smb + LB_ST2);
  float*  cs  = (float*)(smb + LB_CS);
  uint32* A1w = (uint32*)A1h;
  const unsigned short* W3u = (const unsigned short*)W3bf_;
  const unsigned short* W2u = (const unsigned short*)W2bf_;
  const unsigned short* W1u = (const unsigned short*)W1bf_;

  int t = threadIdx.x, bid = blockIdx.x;
  int l = t&63, w = t>>6, cb = l&15, g4 = l>>4;
  int isbf = flagp[0];
  const float* b1=pw+P_B1;  const float* g1=pw+P_G1;  const float* be1=pw+P_BE1;
  const float* b2=pw+P_B2;  const float* g2=pw+P_G2;  const float* be2=pw+P_BE2;
  const float* b3=pw+P_B3;  const float* g3=pw+P_G3;  const float* be3=pw+P_BE3;
  const float* bc=pw+P_BC;

  for(int o=t;o<512;o+=256){ int r=o>>3, dc=24+(o&7); A1w[r*36+dc]=0; }
  {
    int xoff = bid*1200;
    for(int i=t;i<2560;i+=256){
      int r=i/40, c=i-(i/40)*40;
      float v = (r<50 && c<24) ? ldin(x, xoff + r*24+c, isbf) : 0.f;
      XH[i] = (half_t)v;
    }
  }
  __syncthreads();
  {
    f32x4 acc1[3];
    float g1v[3], be1v[3];
    #pragma unroll
    for(int ct=0;ct<3;ct++){
      int col = ct*16 + cb;
      float b = b1[col]; g1v[ct]=g1[col]; be1v[ct]=be1[col];
      acc1[ct][0]=b; acc1[ct][1]=b; acc1[ct][2]=b; acc1[ct][3]=b;
    }
    half8v a = *(const half8v*)(XH + (w*16 + cb)*40 + (g4<<3));
    #pragma unroll
    for(int ct=0;ct<3;ct++){
      half8v b = *(const half8v*)(W1u + (ct*64 + l)*8);
      acc1[ct] = __builtin_amdgcn_mfma_f32_16x16x32_f16(a, b, acc1[ct], 0,0,0);
    }
    __syncthreads();
    #pragma unroll
    for(int r=0;r<4;r++){
      float s1 = acc1[0][r]+acc1[1][r]+acc1[2][r];
      float s2 = acc1[0][r]*acc1[0][r]+acc1[1][r]*acc1[1][r]+acc1[2][r]*acc1[2][r];
      #pragma unroll
      for(int d=1;d<16;d<<=1){ s1+=__shfl_xor(s1,d,64); s2+=__shfl_xor(s2,d,64); }
      float m = s1*(1.f/48.f);
      float var = s2*(1.f/48.f)-m*m;
      float rs = rsqrtf(var+EPSF);
      int row = w*16 + (g4<<2) + r;
      #pragma unroll
      for(int ct=0;ct<3;ct++){
        float val = (acc1[ct][r]-m)*rs*g1v[ct]+be1v[ct];
        A1h[row*72 + ct*16 + cb] = (half_t)fmaxf(val,0.f);
      }
    }
  }
  __syncthreads();
  {
    f32x4 acc2[5];
    #pragma unroll
    for(int ct=0;ct<5;ct++){
      int col = ct*16 + cb;
      float b = (col<72) ? b2[col] : 0.f;
      acc2[ct][0]=b; acc2[ct][1]=b; acc2[ct][2]=b; acc2[ct][3]=b;
    }
    #pragma unroll
    for(int kt=0;kt<2;kt++){
      half8v a = *(const half8v*)(A1h + (w*16 + cb)*72 + kt*32 + (g4<<3));
      #pragma unroll
      for(int ct=0;ct<5;ct++){
        half8v b = *(const half8v*)(W2u + ((ct*2+kt)*64 + l)*8);
        acc2[ct] = __builtin_amdgcn_mfma_f32_16x16x32_f16(a, b, acc2[ct], 0,0,0);
      }
    }
    __syncthreads();
    int valid4 = (cb<8);
    #pragma unroll
    for(int r=0;r<4;r++){
      float s1 = acc2[0][r]+acc2[1][r]+acc2[2][r]+acc2[3][r] + (valid4?acc2[4][r]:0.f);
      float s2 = acc2[0][r]*acc2[0][r]+acc2[1][r]*acc2[1][r]
               + acc2[2][r]*acc2[2][r]+acc2[3][r]*acc2[3][r]
               + (valid4?acc2[4][r]*acc2[4][r]:0.f);
      #pragma unroll
      for(int d=1;d<16;d<<=1){ s1+=__shfl_xor(s1,d,64); s2+=__shfl_xor(s2,d,64); }
      float m = s1*(1.f/72.f);
      float var = s2*(1.f/72.f)-m*m;
      float rs = rsqrtf(var+EPSF);
      int grow = w*16 + (g4<<2) + r;
      #pragma unroll
      for(int ct=0;ct<5;ct++){
        int col = ct*16 + cb;
        if(ct<4 || valid4){
          float val = (acc2[ct][r]-m)*rs*g2[col]+be2[col];
          A2h[grow*104+col] = (half_t)fmaxf(val,0.f);
        }
      }
    }
    uint32* A2w = (uint32*)A2h;
    for(int o=l;o<192;o+=64){ int rr = w*16 + o/12, dc = 36 + (o - (o/12)*12); A2w[rr*52+dc]=0; }
  }
  __syncthreads();
  #pragma unroll 1
  for(int p=0;p<2;p++){
    f32x4 acc[2][4];
    #pragma unroll
    for(int nt=0;nt<4;nt++){
      float b3c = b3[w*64 + nt*16 + cb];
      #pragma unroll
      for(int m2=0;m2<2;m2++){ acc[m2][nt][0]=b3c; acc[m2][nt][1]=b3c; acc[m2][nt][2]=b3c; acc[m2][nt][3]=b3c; }
    }
    #pragma unroll
    for(int kt=0;kt<3;kt++){
      half8v a[2];
      #pragma unroll
      for(int m2=0;m2<2;m2++)
        a[m2] = *(const half8v*)(A2h + ((p*2+m2)*16+cb)*104 + kt*32 + (g4<<3));
      #pragma unroll
      for(int nt=0;nt<4;nt++){
        int ct = w*4 + nt;
        half8v b = *(const half8v*)(W3u + ((ct*3+kt)*64 + l)*8);
        #pragma unroll
        for(int m2=0;m2<2;m2++)
          acc[m2][nt] = __builtin_amdgcn_mfma_f32_16x16x32_f16(a[m2], b, acc[m2][nt], 0,0,0);
      }
    }
    __syncthreads();
    #pragma unroll
    for(int m2=0;m2<2;m2++){
      #pragma unroll
      for(int r=0;r<4;r++){
        int row = (p*2+m2)*16 + (g4<<2) + r;
        float s1 = acc[m2][0][r]+acc[m2][1][r]+acc[m2][2][r]+acc[m2][3][r];
        float s2 = acc[m2][0][r]*acc[m2][0][r]+acc[m2][1][r]*acc[m2][1][r]
                 + acc[m2][2][r]*acc[m2][2][r]+acc[m2][3][r]*acc[m2][3][r];
        #pragma unroll
        for(int d=1;d<16;d<<=1){ s1+=__shfl_xor(s1,d,64); s2+=__shfl_xor(s2,d,64); }
        if(cb==0){
          stw[row*8 + w*2]   = s1;
          stw[row*8 + w*2+1] = s2;
        }
        if(row<50){
          #pragma unroll
          for(int nt=0;nt<4;nt++){
            int col = w*64 + nt*16 + cb;
            if(row<25) H3L[row*256+col]      = (half_t)acc[m2][nt][r];
            else       H3H[(row-25)*256+col] = (half_t)acc[m2][nt][r];
          }
        }
      }
    }
  }
  __syncthreads();
  if(t<64){
    float S1 = stw[t*8+0]+stw[t*8+2]+stw[t*8+4]+stw[t*8+6];
    float S2 = stw[t*8+1]+stw[t*8+3]+stw[t*8+5]+stw[t*8+7];
    float m = S1*(1.f/256.f);
    float var = S2*(1.f/256.f)-m*m;
    st2[2*t]=m; st2[2*t+1]=rsqrtf(var+EPSF);
  }
  __syncthreads();
  {
    uint32* H3l32 = (uint32*)H3L;
    uint32* H3h32 = (uint32*)H3H;
    int cp = t & 127, ro = t>>7;
    float ga=g3[2*cp], gb=g3[2*cp+1], ba=be3[2*cp], bb=be3[2*cp+1];
    for(int r=ro; r<25; r+=2){
      uint32 lo = H3l32[r*128+cp], hi = H3h32[r*128+cp];
      float ml=st2[2*r], rl=st2[2*r+1];
      float mh=st2[2*(r+25)], rh=st2[2*(r+25)+1];
      half2v l2=u2h2(lo), h2=u2h2(hi);
      float v0 = ((float)l2[0]-ml)*rl*ga+ba + ((float)h2[0]-mh)*rh*ga+ba;
      float v1 = ((float)l2[1]-ml)*rl*gb+bb + ((float)h2[1]-mh)*rh*gb+bb;
      H3l32[r*128+cp] = pk2u(v0, v1);
    }
  }
  __syncthreads();
  {
    int cgc = (cb<15)?cb:14;
    int ktbase = w*400 + g4*100;
    const unsigned short* H3u = (const unsigned short*)H3L;
    float a0=0.f,a1=0.f,a2=0.f,a3=0.f;
    for(int i=0;i<100;i++){
      int kt = ktbase + i;
      uint2 hq = *(const uint2*)(H3u + kt*4);
      const uint4* qp = (const uint4*)(Wcp4 + (size_t)(kt*15+cgc)*16);
      uint4 wa = qp[0], wb = qp[1];
      half2v h01 = u2h2(hq.x), h23 = u2h2(hq.y);
      a0 = __builtin_amdgcn_fdot2(h01, u2h2(wa.x), a0, false);
      a0 = __builtin_amdgcn_fdot2(h23, u2h2(wb.x), a0, false);
      a1 = __builtin_amdgcn_fdot2(h01, u2h2(wa.y), a1, false);
      a1 = __builtin_amdgcn_fdot2(h23, u2h2(wb.y), a1, false);
      a2 = __builtin_amdgcn_fdot2(h01, u2h2(wa.z), a2, false);
      a2 = __builtin_amdgcn_fdot2(h23, u2h2(wb.z), a2, false);
      a3 = __builtin_amdgcn_fdot2(h01, u2h2(wa.w), a3, false);
      a3 = __builtin_amdgcn_fdot2(h23, u2h2(wb.w), a3, false);
    }
    a0 += __shfl_xor(a0,16,64); a0 += __shfl_xor(a0,32,64);
    a1 += __shfl_xor(a1,16,64); a1 += __shfl_xor(a1,32,64);
    a2 += __shfl_xor(a2,16,64); a2 += __shfl_xor(a2,32,64);
    a3 += __shfl_xor(a3,16,64); a3 += __shfl_xor(a3,32,64);
    if(l<15){
      cs[w*60 + l*4 + 0] = a0;
      cs[w*60 + l*4 + 1] = a1;
      cs[w*60 + l*4 + 2] = a2;
      cs[w*60 + l*4 + 3] = a3;
    }
  }
  __syncthreads();
  if(t<NC){
    float v = cs[t]+cs[60+t]+cs[120+t]+cs[180+t] + bc[t];
    stout(out, bid*NC+t, isbf, v);
  }
}

__global__ void k4_pred(const void* bm, const int* flagp, void* out){
  int b = blockIdx.x, t = threadIdx.x;
  int isbf = flagp[0];
  if(t<NC){
    float acc=0.f;
    for(int r=0;r<90;r++) acc += ldin(bm, (b*90+r)*NC+t, isbf);
    stout(out, NROW*NC + b*NC + t, isbf, acc*(1.f/90.f));
  }
}

extern "C" void kernel_launch(void* const* d_in, const int* in_sizes, int n_in,
                              void* d_out, int out_size, void* d_ws, size_t ws_size,
                              hipStream_t stream){
  const void* x   = d_in[0];
  const void* adj = d_in[1];
  char* ws = (char*)d_ws;
  int*     flagp = (int*)ws;
  float*   M     = (float*)(ws + WS_M_OFF);
  float*   pw    = (float*)(ws + WS_PW_OFF);
  half_t*  W3bf  = (half_t*)(ws + WS_W3BF_OFF);
  half_t*  W2bf  = (half_t*)(ws + WS_W2BF_OFF);
  half_t*  W1bf  = (half_t*)(ws + WS_W1BF_OFF);
  half_t*  Wcp4  = (half_t*)(ws + WS_WCP_OFF);
  half_t*  Wcpf  = (half_t*)(ws + WS_WCPF_OFF);
  float*   part  = (float*)(ws + WS_PART_OFF);
  half_t*  gH3   = (half_t*)(ws + WS_GH3_OFF);
  bool fast = (ws_size >= WS_NEED);

  if(fast){
    k_prep<<<PREP_K1B+1,256,0,stream>>>(d_in[2],d_in[3],d_in[4],d_in[5],
                                        d_in[6],d_in[7],d_in[8],d_in[9],
                                        d_in[10],d_in[11],d_in[12],d_in[13],
                                        d_in[15], x, adj,
                                        flagp, pw, M, W3bf, W2bf, W1bf);
    k3_fast<<<NB3+NFOLDB,256,0,stream>>>(x, pw, W3bf, W2bf, W1bf,
                                         M, d_in[14], Wcpf, flagp, (uint32*)gH3);
    dim3 g5(45,8);
    k5_gemm<<<g5,256,0,stream>>>(gH3, Wcpf, part);
    k6_out<<<BB,256,0,stream>>>(part, pw, flagp, d_out);
  } else {
    k0_prep<<<1,256,0,stream>>>(x, adj, flagp, M);
    k1_all<<<(R_W1E+255)/256,256,0,stream>>>(d_in[2],d_in[3],d_in[4],d_in[5],
                                             d_in[6],d_in[7],d_in[8],d_in[9],
                                             d_in[10],d_in[11],d_in[12],d_in[13],
                                             d_in[15], flagp, pw, W3bf, W2bf, W1bf);
    k2_fold<<<1500,256,0,stream>>>(d_in[14], M, flagp, Wcp4);
    k3_fused<<<NROW,256,0,stream>>>(x, pw, W3bf, W2bf, W1bf,
                                    (const unsigned short*)Wcp4, flagp, d_out);
    k4_pred<<<BB,64,0,stream>>>(d_out, flagp, d_out);
  }
}

// Round 20
// 95.816 us; speedup vs baseline: 1.3822x; 1.3822x over previous
//
#include <hip/hip_runtime.h>
#include <hip/hip_bf16.h>

typedef __hip_bfloat16 bf16t;
typedef _Float16 half_t;
typedef __attribute__((ext_vector_type(2))) _Float16 half2v;
typedef __attribute__((ext_vector_type(8))) _Float16 half8v;
typedef __attribute__((ext_vector_type(4))) float f32x4;
typedef unsigned int uint32;

#define BB   32
#define NC   60
#define NROW 2880
#define NFOLDB 1600
#define EPSF 1e-5f
#define ALPHA 0.2f
#define DEG  4

// ws layout (bytes). Slow path <=869376 (proven). Fast path <=44450816 (proven).
#define WS_M_OFF    256
#define WS_PW_OFF   4096
#define WS_W3BF_OFF 28672
#define WS_W2BF_OFF 77824
#define WS_W1BF_OFF 88064
#define WS_WCP_OFF  101376
#define WS_WCPF_OFF 869376
#define WS_PART_OFF 1688576
#define WS_GH3_OFF  7586816
#define WS_NEED     44450816ULL

// pw float offsets
#define P_W1  0
#define P_B1  1152
#define P_G1  1200
#define P_BE1 1248
#define P_W2  1296
#define P_B2  4752
#define P_G2  4824
#define P_BE2 4896
#define P_B3  4968
#define P_G3  5224
#define P_BE3 5480
#define P_BC  5736
#define P_TOT 5796
#define R_W3E (P_TOT+24576)
#define R_W2E (R_W3E+5120)
#define R_W1E (R_W2E+1536)
#define PREP_K1B 145            // ceil(R_W1E/256); block 145 builds M

// k3 LDS byte offsets (37888 B; R12-proven)
#define LB_H3L 0        // f16 [25][256] raw h3 rows 0..24
#define LB_A1  12800    // f16 [64][72]
#define LB_CS  12800    // float[240] overlay on A1 (fused classifier phase only)
#define LB_A2  22016    // f16 [64][104]
#define LB_H3H 22016    // f16 [25][256] raw h3 rows 25..49, overlays A2
#define LB_STW 35328    // float[512]
#define LB_ST2 37376    // float[128]
#define LDS_FTOT 9472   // 37888 B

__device__ __forceinline__ float ldin(const void* p, int i, int isbf){
  return isbf ? __bfloat162float(((const bf16t*)p)[i]) : ((const float*)p)[i];
}
__device__ __forceinline__ void stout(void* p, int i, int isbf, float v){
  if(isbf) ((bf16t*)p)[i] = __float2bfloat16(v);
  else     ((float*)p)[i] = v;
}
__device__ __forceinline__ half2v u2h2(uint32 u){
  half2v h; __builtin_memcpy(&h,&u,4); return h;
}
__device__ __forceinline__ uint32 pk2u(float a, float b){
  auto r = __builtin_amdgcn_cvt_pkrtz(a, b);
  uint32 u; __builtin_memcpy(&u,&r,4); return u;
}

// ======================= FAST PATH =======================

// ---- k_prep: dtype-detect + param packs; block 145 builds M -> ws
__global__ void k_prep(const void* W1,const void* b1,const void* g1,const void* be1,
                       const void* W2,const void* b2,const void* g2,const void* be2,
                       const void* W3,const void* b3,const void* g3,const void* be3,
                       const void* bc, const void* x, const void* adj,
                       int* flagp, float* pw, float* M,
                       half_t* W3bf, half_t* W2bf, half_t* W1bf){
  __shared__ float A[625], Pp[625], Q[625], Ss[625];
  __shared__ int cnt;
  int t = threadIdx.x, bid = blockIdx.x;
  if(t==0) cnt = 0;
  __syncthreads();
  {
    const unsigned short* xb = (const unsigned short*)x;
    unsigned short u = xb[2*t];
    int e = (u>>7)&0xFF;
    if(e>=100 && e<=141) atomicAdd(&cnt,1);
  }
  __syncthreads();
  int isbf = (cnt>=160) ? 1 : 0;
  if(bid==0 && t==0) flagp[0] = isbf;

  if(bid < PREP_K1B){
    int o = bid*256 + t;
    if(o < P_TOT){
      const void* src; int loc;
      if      (o < P_B1 ) { src=W1;  loc=o;        }
      else if (o < P_G1 ) { src=b1;  loc=o-P_B1;   }
      else if (o < P_BE1) { src=g1;  loc=o-P_G1;   }
      else if (o < P_W2 ) { src=be1; loc=o-P_BE1;  }
      else if (o < P_B2 ) { src=W2;  loc=o-P_W2;   }
      else if (o < P_G2 ) { src=b2;  loc=o-P_B2;   }
      else if (o < P_BE2) { src=g2;  loc=o-P_G2;   }
      else if (o < P_B3 ) { src=be2; loc=o-P_BE2;  }
      else if (o < P_G3 ) { src=b3;  loc=o-P_B3;   }
      else if (o < P_BE3) { src=g3;  loc=o-P_G3;   }
      else if (o < P_BC ) { src=be3; loc=o-P_BE3;  }
      else                { src=bc;  loc=o-P_BC;   }
      pw[o] = ldin(src, loc, isbf);
    } else if(o < R_W3E){
      int o2 = o - P_TOT;
      int ct = o2/1536, rem = o2 - ct*1536;
      int kt = rem/512, rem2 = rem - kt*512;
      int l = rem2>>3, j = rem2&7;
      int k = kt*32 + ((l>>4)<<3) + j;
      int col = (ct<<4) + (l&15);
      float v = (k<72) ? ldin(W3, k*256+col, isbf) : 0.f;
      W3bf[o2] = (half_t)v;
    } else if(o < R_W2E){
      int o2 = o - R_W3E;
      int ct = o2/1024, rem = o2 - ct*1024;
      int kt = rem/512, rem2 = rem - kt*512;
      int l = rem2>>3, j = rem2&7;
      int k = kt*32 + ((l>>4)<<3) + j;
      int col = (ct<<4) + (l&15);
      float v = (k<48 && col<72) ? ldin(W2, k*72+col, isbf) : 0.f;
      W2bf[o2] = (half_t)v;
    } else if(o < R_W1E){
      int o2 = o - R_W2E;
      int ct = o2/512, rem2 = o2 - ct*512;
      int l = rem2>>3, j = rem2&7;
      int k = ((l>>4)<<3) + j;
      int col = (ct<<4) + (l&15);
      float v = (k<24) ? ldin(W1, k*48+col, isbf) : 0.f;
      W1bf[o2] = (half_t)v;
    }
  } else {
    for(int i=t;i<625;i+=256){ float a=ldin(adj,i,isbf); A[i]=a; Pp[i]=a; Ss[i]=a; }
    __syncthreads();
    for(int d=1; d<DEG; ++d){
      for(int o=t;o<625;o+=256){
        int i=o/25, j=o%25; float acc=0.f;
        for(int k=0;k<25;k++) acc += A[i*25+k]*Pp[k*25+j];
        Q[o]=acc;
      }
      __syncthreads();
      for(int o=t;o<625;o+=256){ Pp[o]=Q[o]; Ss[o]+=Q[o]; }
      __syncthreads();
    }
    const float coef = (1.0f-ALPHA)/(float)DEG;
    for(int o=t;o<625;o+=256){
      int i=o/25, j=o%25;
      M[o] = (i==j ? ALPHA : 0.0f) + coef*Ss[o];
    }
  }
}

// ---- k3c: blocks [0,2880) = MLP pipeline (6 barriers, direct-x);
//           blocks [2880,4480) = Wcpf fold
__global__ __launch_bounds__(256,4) void k3_fast(const void* x, const float* pw,
                                              const half_t* W3bf_, const half_t* W2bf_,
                                              const half_t* W1bf_,
                                              const float* M, const void* Wc,
                                              half_t* Wcpf,
                                              const int* flagp, uint32* gH3d){
  __shared__ float sm[LDS_FTOT];
  char* smb = (char*)sm;
  half_t* H3L = (half_t*)(smb + LB_H3L);
  half_t* H3H = (half_t*)(smb + LB_H3H);   // overlays A2
  half_t* A1h = (half_t*)(smb + LB_A1);
  half_t* A2h = (half_t*)(smb + LB_A2);
  float*  stw = (float*)(smb + LB_STW);
  float*  st2 = (float*)(smb + LB_ST2);
  uint32* A1w = (uint32*)A1h;
  const unsigned short* W3u = (const unsigned short*)W3bf_;
  const unsigned short* W2u = (const unsigned short*)W2bf_;
  const unsigned short* W1u = (const unsigned short*)W1bf_;

  int t = threadIdx.x, bid = blockIdx.x;
  int isbf = flagp[0];

  if(bid >= NROW){
    // ---- fold body: Wcpf [kst][nt][lane][8] (R12 K-linear pairing); M from ws
    int o = (bid-NROW)*256 + t;   // exact 409600
    int j = o&7, l = (o>>3)&63, nt = (o>>9)&3, kst = o>>11;
    int k = kst*32 + ((l>>4)<<3) + j;
    int c = nt*16 + (l&15);
    float acc = 0.f;
    if(c < 60){
      int jj = k>>8, f = k&255;
      for(int i=0;i<25;i++) acc += M[i*25+jj]*ldin(Wc, (i*256+f)*60 + c, isbf);
    }
    Wcpf[o] = (half_t)(0.5f*acc);
    return;
  }

  int l = t&63, w = t>>6, cb = l&15, g4 = l>>4;
  const float* b1=pw+P_B1;  const float* g1=pw+P_G1;  const float* be1=pw+P_BE1;
  const float* b2=pw+P_B2;  const float* g2=pw+P_G2;  const float* be2=pw+P_BE2;
  const float* b3=pw+P_B3;  const float* g3=pw+P_G3;  const float* be3=pw+P_BE3;

  // phase 0: zero A1 col-pad 48..63 (cross-wave; drains under MFMA1's global loads)
  for(int o=t;o<512;o+=256){ int r=o>>3, dc=24+(o&7); A1w[r*36+dc]=0; }

  // ---- MFMA1: A direct from global x; B from W1bf; no LDS deps
  {
    f32x4 acc1[3];
    float g1v[3], be1v[3];
    #pragma unroll
    for(int ct=0;ct<3;ct++){
      int col = ct*16 + cb;
      float b = b1[col]; g1v[ct]=g1[col]; be1v[ct]=be1[col];
      acc1[ct][0]=b; acc1[ct][1]=b; acc1[ct][2]=b; acc1[ct][3]=b;
    }
    int row = w*16 + cb;
    half8v a;
    if(g4 < 3 && row < 50){
      int base = bid*1200 + row*24 + g4*8;
      #pragma unroll
      for(int j=0;j<8;j++) a[j] = (half_t)ldin(x, base+j, isbf);
    } else {
      #pragma unroll
      for(int j=0;j<8;j++) a[j] = (half_t)0.f;
    }
    #pragma unroll
    for(int ct=0;ct<3;ct++){
      half8v b = *(const half8v*)(W1u + (ct*64 + l)*8);
      acc1[ct] = __builtin_amdgcn_mfma_f32_16x16x32_f16(a, b, acc1[ct], 0,0,0);
    }
    __syncthreads();   // S1: phase-0 pad zeros visible before MFMA2's A1 reads
    #pragma unroll
    for(int r=0;r<4;r++){
      float s1 = acc1[0][r]+acc1[1][r]+acc1[2][r];
      float s2 = acc1[0][r]*acc1[0][r]+acc1[1][r]*acc1[1][r]+acc1[2][r]*acc1[2][r];
      #pragma unroll
      for(int d=1;d<16;d<<=1){ s1+=__shfl_xor(s1,d,64); s2+=__shfl_xor(s2,d,64); }
      float m = s1*(1.f/48.f);
      float var = s2*(1.f/48.f)-m*m;
      float rs = rsqrtf(var+EPSF);
      int rw = w*16 + (g4<<2) + r;
      #pragma unroll
      for(int ct=0;ct<3;ct++){
        float val = (acc1[ct][r]-m)*rs*g1v[ct]+be1v[ct];
        A1h[rw*72 + ct*16 + cb] = (half_t)fmaxf(val,0.f);
      }
    }
  }
  // no barrier: A1 written own-wave rows, read own-wave rows below

  // ---- MFMA2
  {
    f32x4 acc2[5];
    #pragma unroll
    for(int ct=0;ct<5;ct++){
      int col = ct*16 + cb;
      float b = (col<72) ? b2[col] : 0.f;
      acc2[ct][0]=b; acc2[ct][1]=b; acc2[ct][2]=b; acc2[ct][3]=b;
    }
    #pragma unroll
    for(int kt=0;kt<2;kt++){
      half8v a = *(const half8v*)(A1h + (w*16 + cb)*72 + kt*32 + (g4<<3));
      #pragma unroll
      for(int ct=0;ct<5;ct++){
        half8v b = *(const half8v*)(W2u + ((ct*2+kt)*64 + l)*8);
        acc2[ct] = __builtin_amdgcn_mfma_f32_16x16x32_f16(a, b, acc2[ct], 0,0,0);
      }
    }
    int valid4 = (cb<8);
    #pragma unroll
    for(int r=0;r<4;r++){
      float s1 = acc2[0][r]+acc2[1][r]+acc2[2][r]+acc2[3][r] + (valid4?acc2[4][r]:0.f);
      float s2 = acc2[0][r]*acc2[0][r]+acc2[1][r]*acc2[1][r]
               + acc2[2][r]*acc2[2][r]+acc2[3][r]*acc2[3][r]
               + (valid4?acc2[4][r]*acc2[4][r]:0.f);
      #pragma unroll
      for(int d=1;d<16;d<<=1){ s1+=__shfl_xor(s1,d,64); s2+=__shfl_xor(s2,d,64); }
      float m = s1*(1.f/72.f);
      float var = s2*(1.f/72.f)-m*m;
      float rs = rsqrtf(var+EPSF);
      int grow = w*16 + (g4<<2) + r;
      #pragma unroll
      for(int ct=0;ct<5;ct++){
        int col = ct*16 + cb;
        if(ct<4 || valid4){
          float val = (acc2[ct][r]-m)*rs*g2[col]+be2[col];
          A2h[grow*104+col] = (half_t)fmaxf(val,0.f);
        }
      }
    }
    // zero A2 k-pad cols 72..95 for own rows
    uint32* A2w = (uint32*)A2h;
    for(int o=l;o<192;o+=64){ int rr = w*16 + o/12, dc = 36 + (o - (o/12)*12); A2w[rr*52+dc]=0; }
  }
  __syncthreads();   // S2: A2 complete before all-row MFMA3 reads

  // ---- MFMA3: hoisted W3 B-fragments (pass-invariant), two M-passes
  half8v bfr[12];
  #pragma unroll
  for(int kt=0;kt<3;kt++){
    #pragma unroll
    for(int nt=0;nt<4;nt++)
      bfr[kt*4+nt] = *(const half8v*)(W3u + (((w*4+nt)*3+kt)*64 + l)*8);
  }
  float b3v[4];
  #pragma unroll
  for(int nt=0;nt<4;nt++) b3v[nt] = b3[w*64 + nt*16 + cb];

  #pragma unroll 1
  for(int p=0;p<2;p++){
    f32x4 acc[2][4];
    #pragma unroll
    for(int nt=0;nt<4;nt++){
      #pragma unroll
      for(int m2=0;m2<2;m2++){ acc[m2][nt][0]=b3v[nt]; acc[m2][nt][1]=b3v[nt]; acc[m2][nt][2]=b3v[nt]; acc[m2][nt][3]=b3v[nt]; }
    }
    #pragma unroll
    for(int kt=0;kt<3;kt++){
      half8v a[2];
      #pragma unroll
      for(int m2=0;m2<2;m2++)
        a[m2] = *(const half8v*)(A2h + ((p*2+m2)*16+cb)*104 + kt*32 + (g4<<3));
      #pragma unroll
      for(int nt=0;nt<4;nt++){
        #pragma unroll
        for(int m2=0;m2<2;m2++)
          acc[m2][nt] = __builtin_amdgcn_mfma_f32_16x16x32_f16(a[m2], bfr[kt*4+nt], acc[m2][nt], 0,0,0);
      }
    }
    __syncthreads();   // S3/S4: A2 reads done before H3H-overlay writes
    #pragma unroll
    for(int m2=0;m2<2;m2++){
      #pragma unroll
      for(int r=0;r<4;r++){
        int row = (p*2+m2)*16 + (g4<<2) + r;
        float s1 = acc[m2][0][r]+acc[m2][1][r]+acc[m2][2][r]+acc[m2][3][r];
        float s2 = acc[m2][0][r]*acc[m2][0][r]+acc[m2][1][r]*acc[m2][1][r]
                 + acc[m2][2][r]*acc[m2][2][r]+acc[m2][3][r]*acc[m2][3][r];
        #pragma unroll
        for(int d=1;d<16;d<<=1){ s1+=__shfl_xor(s1,d,64); s2+=__shfl_xor(s2,d,64); }
        if(cb==0){
          stw[row*8 + w*2]   = s1;
          stw[row*8 + w*2+1] = s2;
        }
        if(row<50){
          #pragma unroll
          for(int nt=0;nt<4;nt++){
            int col = w*64 + nt*16 + cb;
            if(row<25) H3L[row*256+col]      = (half_t)acc[m2][nt][r];
            else       H3H[(row-25)*256+col] = (half_t)acc[m2][nt][r];
          }
        }
      }
    }
  }
  __syncthreads();   // S5
  if(t<64){
    float S1 = stw[t*8+0]+stw[t*8+2]+stw[t*8+4]+stw[t*8+6];
    float S2 = stw[t*8+1]+stw[t*8+3]+stw[t*8+5]+stw[t*8+7];
    float m = S1*(1.f/256.f);
    float var = S2*(1.f/256.f)-m*m;
    st2[2*t]=m; st2[2*t+1]=rsqrtf(var+EPSF);
  }
  __syncthreads();   // S6
  // LN3 scale + s-sum -> gH3 (per-thread uint32; R12-proven clean write pattern)
  {
    uint32* H3l32 = (uint32*)H3L;
    uint32* H3h32 = (uint32*)H3H;
    int cp = t & 127, ro = t>>7;
    float ga=g3[2*cp], gb=g3[2*cp+1], ba=be3[2*cp], bb=be3[2*cp+1];
    for(int r=ro; r<25; r+=2){
      uint32 lo = H3l32[r*128+cp], hi = H3h32[r*128+cp];
      float ml=st2[2*r], rl=st2[2*r+1];
      float mh=st2[2*(r+25)], rh=st2[2*(r+25)+1];
      half2v l2=u2h2(lo), h2=u2h2(hi);
      float v0 = ((float)l2[0]-ml)*rl*ga+ba + ((float)h2[0]-mh)*rh*ga+ba;
      float v1 = ((float)l2[1]-ml)*rl*gb+bb + ((float)h2[1]-mh)*rh*gb+bb;
      gH3d[(size_t)bid*3200 + r*128 + cp] = pk2u(v0, v1);
    }
  }
}

// ---- k5: GEMM [2880,6400]@[6400,64p]; grid (45, 8)
__global__ __launch_bounds__(256) void k5_gemm(const half_t* gH3, const half_t* Wcpf,
                                               float* part){
  int bx = blockIdx.x, ky = blockIdx.y;
  int t = threadIdx.x, l = t&63, w = t>>6, cb = l&15, g4 = l>>4;
  const unsigned short* H = (const unsigned short*)gH3;
  const unsigned short* W = (const unsigned short*)Wcpf;
  int base = bx*64 + w*16;
  f32x4 acc[4];
  #pragma unroll
  for(int nt=0;nt<4;nt++){ acc[nt][0]=0.f; acc[nt][1]=0.f; acc[nt][2]=0.f; acc[nt][3]=0.f; }
  int kst0 = ky*25;
  for(int ks=0;ks<25;ks++){
    int kst = kst0 + ks;
    half8v a = *(const half8v*)(H + (size_t)(base+cb)*6400 + kst*32 + (g4<<3));
    #pragma unroll
    for(int nt=0;nt<4;nt++){
      half8v b = *(const half8v*)(W + ((kst*4+nt)*64 + l)*8);
      acc[nt] = __builtin_amdgcn_mfma_f32_16x16x32_f16(a, b, acc[nt], 0,0,0);
    }
  }
  #pragma unroll
  for(int nt=0;nt<4;nt++){
    #pragma unroll
    for(int r=0;r<4;r++){
      int inst = base + (g4<<2) + r;
      part[((size_t)ky*NROW + inst)*64 + nt*16 + cb] = acc[nt][r];
    }
  }
}

// ---- k6_out: fused block_mean (+bias, 8 partials) and pred; grid 32
__global__ void k6_out(const float* part, const float* pw, const int* flagp, void* out){
  __shared__ float bm[5400];
  int b = blockIdx.x, t = threadIdx.x;
  int isbf = flagp[0];
  for(int o=t;o<5400;o+=256){
    int li = o/60, c = o - li*60;
    int inst = b*90 + li;
    float v = pw[P_BC + c];
    #pragma unroll
    for(int ky=0;ky<8;ky++) v += part[((size_t)ky*NROW + inst)*64 + c];
    bm[o] = v;
    stout(out, inst*NC + c, isbf, v);
  }
  __syncthreads();
  if(t<NC){
    float a = 0.f;
    for(int r=0;r<90;r++) a += bm[r*60+t];
    stout(out, NROW*NC + b*NC + t, isbf, a*(1.f/90.f));
  }
}

// ======================= SLOW PATH (fallback, proven) =======================

__global__ void k0_prep(const void* x, const void* adj, int* flagp, float* M){
  __shared__ float A[625], P[625], Q[625], Ss[625];
  __shared__ int cnt, flg;
  int t = threadIdx.x;
  if(t==0) cnt = 0;
  __syncthreads();
  {
    const unsigned short* xb = (const unsigned short*)x;
    unsigned short u = xb[2*t];
    int e = (u>>7)&0xFF;
    if(e>=100 && e<=141) atomicAdd(&cnt,1);
  }
  __syncthreads();
  if(t==0){ flg = (cnt>=160)?1:0; flagp[0]=flg; }
  __syncthreads();
  int isbf = flg;
  for(int i=t;i<625;i+=256){ float a=ldin(adj,i,isbf); A[i]=a; P[i]=a; Ss[i]=a; }
  __syncthreads();
  for(int d=1; d<DEG; ++d){
    for(int o=t;o<625;o+=256){
      int i=o/25, j=o%25; float acc=0.f;
      for(int k=0;k<25;k++) acc += A[i*25+k]*P[k*25+j];
      Q[o]=acc;
    }
    __syncthreads();
    for(int o=t;o<625;o+=256){ P[o]=Q[o]; Ss[o]+=Q[o]; }
    __syncthreads();
  }
  const float coef = (1.0f-ALPHA)/(float)DEG;
  for(int o=t;o<625;o+=256){
    int i=o/25, j=o%25;
    M[o] = (i==j ? ALPHA : 0.0f) + coef*Ss[o];
  }
}

__global__ void k1_all(const void* W1,const void* b1,const void* g1,const void* be1,
                       const void* W2,const void* b2,const void* g2,const void* be2,
                       const void* W3,const void* b3,const void* g3,const void* be3,
                       const void* bc, const int* flagp,
                       float* pw, half_t* W3bf, half_t* W2bf, half_t* W1bf){
  int isbf = flagp[0];
  int o = blockIdx.x*256 + threadIdx.x;
  if(o < P_TOT){
    const void* src; int loc;
    if      (o < P_B1 ) { src=W1;  loc=o;        }
    else if (o < P_G1 ) { src=b1;  loc=o-P_B1;   }
    else if (o < P_BE1) { src=g1;  loc=o-P_G1;   }
    else if (o < P_W2 ) { src=be1; loc=o-P_BE1;  }
    else if (o < P_B2 ) { src=W2;  loc=o-P_W2;   }
    else if (o < P_G2 ) { src=b2;  loc=o-P_B2;   }
    else if (o < P_BE2) { src=g2;  loc=o-P_G2;   }
    else if (o < P_B3 ) { src=be2; loc=o-P_BE2;  }
    else if (o < P_G3 ) { src=b3;  loc=o-P_B3;   }
    else if (o < P_BE3) { src=g3;  loc=o-P_G3;   }
    else if (o < P_BC ) { src=be3; loc=o-P_BE3;  }
    else                { src=bc;  loc=o-P_BC;   }
    pw[o] = ldin(src, loc, isbf);
  } else if(o < R_W3E){
    int o2 = o - P_TOT;
    int ct = o2/1536, rem = o2 - ct*1536;
    int kt = rem/512, rem2 = rem - kt*512;
    int l = rem2>>3, j = rem2&7;
    int k = kt*32 + ((l>>4)<<3) + j;
    int col = (ct<<4) + (l&15);
    float v = (k<72) ? ldin(W3, k*256+col, isbf) : 0.f;
    W3bf[o2] = (half_t)v;
  } else if(o < R_W2E){
    int o2 = o - R_W3E;
    int ct = o2/1024, rem = o2 - ct*1024;
    int kt = rem/512, rem2 = rem - kt*512;
    int l = rem2>>3, j = rem2&7;
    int k = kt*32 + ((l>>4)<<3) + j;
    int col = (ct<<4) + (l&15);
    float v = (k<48 && col<72) ? ldin(W2, k*72+col, isbf) : 0.f;
    W2bf[o2] = (half_t)v;
  } else if(o < R_W1E){
    int o2 = o - R_W2E;
    int ct = o2/512, rem2 = o2 - ct*512;
    int l = rem2>>3, j = rem2&7;
    int k = ((l>>4)<<3) + j;
    int col = (ct<<4) + (l&15);
    float v = (k<24) ? ldin(W1, k*48+col, isbf) : 0.f;
    W1bf[o2] = (half_t)v;
  }
}

__global__ void k2_fold(const void* Wc, const float* M, const int* flagp, half_t* Wcp4){
  int isbf = flagp[0];
  int o = blockIdx.x*256 + threadIdx.x;
  if(o >= 384000) return;
  int grp = o>>4, hw = o&15;
  int kt = grp/15, cg = grp - kt*15;
  int p = hw>>3, cl = (hw>>1)&3, e = hw&1;
  int fl = kt*4 + 2*p + e;
  int j = fl>>8, f = fl&255;
  int c = cg*4 + cl;
  float acc = 0.f;
  for(int i=0;i<25;i++) acc += M[i*25+j]*ldin(Wc, (i*256+f)*60 + c, isbf);
  Wcp4[o] = (half_t)(0.5f*acc);
}

__global__ __launch_bounds__(256,4) void k3_fused(const void* x, const float* pw,
                                              const half_t* W3bf_, const half_t* W2bf_,
                                              const half_t* W1bf_,
                                              const unsigned short* Wcp4,
                                              const int* flagp, void* out){
  __shared__ float sm[LDS_FTOT];
  char* smb = (char*)sm;
  half_t* H3L = (half_t*)(smb + LB_H3L);
  half_t* H3H = (half_t*)(smb + LB_H3H);
  half_t* A1h = (half_t*)(smb + LB_A1);
  half_t* A2h = (half_t*)(smb + LB_A2);
  half_t* XH  = A2h;
  float*  stw = (float*)(smb + LB_STW);
  float*  st2 = (float*)(smb + LB_ST2);
  float*  cs  = (float*)(smb + LB_CS);
  uint32* A1w = (uint32*)A1h;
  const unsigned short* W3u = (const unsigned short*)W3bf_;
  const unsigned short* W2u = (const unsigned short*)W2bf_;
  const unsigned short* W1u = (const unsigned short*)W1bf_;

  int t = threadIdx.x, bid = blockIdx.x;
  int l = t&63, w = t>>6, cb = l&15, g4 = l>>4;
  int isbf = flagp[0];
  const float* b1=pw+P_B1;  const float* g1=pw+P_G1;  const float* be1=pw+P_BE1;
  const float* b2=pw+P_B2;  const float* g2=pw+P_G2;  const float* be2=pw+P_BE2;
  const float* b3=pw+P_B3;  const float* g3=pw+P_G3;  const float* be3=pw+P_BE3;
  const float* bc=pw+P_BC;

  for(int o=t;o<512;o+=256){ int r=o>>3, dc=24+(o&7); A1w[r*36+dc]=0; }
  {
    int xoff = bid*1200;
    for(int i=t;i<2560;i+=256){
      int r=i/40, c=i-(i/40)*40;
      float v = (r<50 && c<24) ? ldin(x, xoff + r*24+c, isbf) : 0.f;
      XH[i] = (half_t)v;
    }
  }
  __syncthreads();
  {
    f32x4 acc1[3];
    float g1v[3], be1v[3];
    #pragma unroll
    for(int ct=0;ct<3;ct++){
      int col = ct*16 + cb;
      float b = b1[col]; g1v[ct]=g1[col]; be1v[ct]=be1[col];
      acc1[ct][0]=b; acc1[ct][1]=b; acc1[ct][2]=b; acc1[ct][3]=b;
    }
    half8v a = *(const half8v*)(XH + (w*16 + cb)*40 + (g4<<3));
    #pragma unroll
    for(int ct=0;ct<3;ct++){
      half8v b = *(const half8v*)(W1u + (ct*64 + l)*8);
      acc1[ct] = __builtin_amdgcn_mfma_f32_16x16x32_f16(a, b, acc1[ct], 0,0,0);
    }
    __syncthreads();
    #pragma unroll
    for(int r=0;r<4;r++){
      float s1 = acc1[0][r]+acc1[1][r]+acc1[2][r];
      float s2 = acc1[0][r]*acc1[0][r]+acc1[1][r]*acc1[1][r]+acc1[2][r]*acc1[2][r];
      #pragma unroll
      for(int d=1;d<16;d<<=1){ s1+=__shfl_xor(s1,d,64); s2+=__shfl_xor(s2,d,64); }
      float m = s1*(1.f/48.f);
      float var = s2*(1.f/48.f)-m*m;
      float rs = rsqrtf(var+EPSF);
      int row = w*16 + (g4<<2) + r;
      #pragma unroll
      for(int ct=0;ct<3;ct++){
        float val = (acc1[ct][r]-m)*rs*g1v[ct]+be1v[ct];
        A1h[row*72 + ct*16 + cb] = (half_t)fmaxf(val,0.f);
      }
    }
  }
  __syncthreads();
  {
    f32x4 acc2[5];
    #pragma unroll
    for(int ct=0;ct<5;ct++){
      int col = ct*16 + cb;
      float b = (col<72) ? b2[col] : 0.f;
      acc2[ct][0]=b; acc2[ct][1]=b; acc2[ct][2]=b; acc2[ct][3]=b;
    }
    #pragma unroll
    for(int kt=0;kt<2;kt++){
      half8v a = *(const half8v*)(A1h + (w*16 + cb)*72 + kt*32 + (g4<<3));
      #pragma unroll
      for(int ct=0;ct<5;ct++){
        half8v b = *(const half8v*)(W2u + ((ct*2+kt)*64 + l)*8);
        acc2[ct] = __builtin_amdgcn_mfma_f32_16x16x32_f16(a, b, acc2[ct], 0,0,0);
      }
    }
    __syncthreads();
    int valid4 = (cb<8);
    #pragma unroll
    for(int r=0;r<4;r++){
      float s1 = acc2[0][r]+acc2[1][r]+acc2[2][r]+acc2[3][r] + (valid4?acc2[4][r]:0.f);
      float s2 = acc2[0][r]*acc2[0][r]+acc2[1][r]*acc2[1][r]
               + acc2[2][r]*acc2[2][r]+acc2[3][r]*acc2[3][r]
               + (valid4?acc2[4][r]*acc2[4][r]:0.f);
      #pragma unroll
      for(int d=1;d<16;d<<=1){ s1+=__shfl_xor(s1,d,64); s2+=__shfl_xor(s2,d,64); }
      float m = s1*(1.f/72.f);
      float var = s2*(1.f/72.f)-m*m;
      float rs = rsqrtf(var+EPSF);
      int grow = w*16 + (g4<<2) + r;
      #pragma unroll
      for(int ct=0;ct<5;ct++){
        int col = ct*16 + cb;
        if(ct<4 || valid4){
          float val = (acc2[ct][r]-m)*rs*g2[col]+be2[col];
          A2h[grow*104+col] = (half_t)fmaxf(val,0.f);
        }
      }
    }
    uint32* A2w = (uint32*)A2h;
    for(int o=l;o<192;o+=64){ int rr = w*16 + o/12, dc = 36 + (o - (o/12)*12); A2w[rr*52+dc]=0; }
  }
  __syncthreads();
  #pragma unroll 1
  for(int p=0;p<2;p++){
    f32x4 acc[2][4];
    #pragma unroll
    for(int nt=0;nt<4;nt++){
      float b3c = b3[w*64 + nt*16 + cb];
      #pragma unroll
      for(int m2=0;m2<2;m2++){ acc[m2][nt][0]=b3c; acc[m2][nt][1]=b3c; acc[m2][nt][2]=b3c; acc[m2][nt][3]=b3c; }
    }
    #pragma unroll
    for(int kt=0;kt<3;kt++){
      half8v a[2];
      #pragma unroll
      for(int m2=0;m2<2;m2++)
        a[m2] = *(const half8v*)(A2h + ((p*2+m2)*16+cb)*104 + kt*32 + (g4<<3));
      #pragma unroll
      for(int nt=0;nt<4;nt++){
        int ct = w*4 + nt;
        half8v b = *(const half8v*)(W3u + ((ct*3+kt)*64 + l)*8);
        #pragma unroll
        for(int m2=0;m2<2;m2++)
          acc[m2][nt] = __builtin_amdgcn_mfma_f32_16x16x32_f16(a[m2], b, acc[m2][nt], 0,0,0);
      }
    }
    __syncthreads();
    #pragma unroll
    for(int m2=0;m2<2;m2++){
      #pragma unroll
      for(int r=0;r<4;r++){
        int row = (p*2+m2)*16 + (g4<<2) + r;
        float s1 = acc[m2][0][r]+acc[m2][1][r]+acc[m2][2][r]+acc[m2][3][r];
        float s2 = acc[m2][0][r]*acc[m2][0][r]+acc[m2][1][r]*acc[m2][1][r]
                 + acc[m2][2][r]*acc[m2][2][r]+acc[m2][3][r]*acc[m2][3][r];
        #pragma unroll
        for(int d=1;d<16;d<<=1){ s1+=__shfl_xor(s1,d,64); s2+=__shfl_xor(s2,d,64); }
        if(cb==0){
          stw[row*8 + w*2]   = s1;
          stw[row*8 + w*2+1] = s2;
        }
        if(row<50){
          #pragma unroll
          for(int nt=0;nt<4;nt++){
            int col = w*64 + nt*16 + cb;
            if(row<25) H3L[row*256+col]      = (half_t)acc[m2][nt][r];
            else       H3H[(row-25)*256+col] = (half_t)acc[m2][nt][r];
          }
        }
      }
    }
  }
  __syncthreads();
  if(t<64){
    float S1 = stw[t*8+0]+stw[t*8+2]+stw[t*8+4]+stw[t*8+6];
    float S2 = stw[t*8+1]+stw[t*8+3]+stw[t*8+5]+stw[t*8+7];
    float m = S1*(1.f/256.f);
    float var = S2*(1.f/256.f)-m*m;
    st2[2*t]=m; st2[2*t+1]=rsqrtf(var+EPSF);
  }
  __syncthreads();
  {
    uint32* H3l32 = (uint32*)H3L;
    uint32* H3h32 = (uint32*)H3H;
    int cp = t & 127, ro = t>>7;
    float ga=g3[2*cp], gb=g3[2*cp+1], ba=be3[2*cp], bb=be3[2*cp+1];
    for(int r=ro; r<25; r+=2){
      uint32 lo = H3l32[r*128+cp], hi = H3h32[r*128+cp];
      float ml=st2[2*r], rl=st2[2*r+1];
      float mh=st2[2*(r+25)], rh=st2[2*(r+25)+1];
      half2v l2=u2h2(lo), h2=u2h2(hi);
      float v0 = ((float)l2[0]-ml)*rl*ga+ba + ((float)h2[0]-mh)*rh*ga+ba;
      float v1 = ((float)l2[1]-ml)*rl*gb+bb + ((float)h2[1]-mh)*rh*gb+bb;
      H3l32[r*128+cp] = pk2u(v0, v1);
    }
  }
  __syncthreads();
  {
    int cgc = (cb<15)?cb:14;
    int ktbase = w*400 + g4*100;
    const unsigned short* H3u = (const unsigned short*)H3L;
    float a0=0.f,a1=0.f,a2=0.f,a3=0.f;
    for(int i=0;i<100;i++){
      int kt = ktbase + i;
      uint2 hq = *(const uint2*)(H3u + kt*4);
      const uint4* qp = (const uint4*)(Wcp4 + (size_t)(kt*15+cgc)*16);
      uint4 wa = qp[0], wb = qp[1];
      half2v h01 = u2h2(hq.x), h23 = u2h2(hq.y);
      a0 = __builtin_amdgcn_fdot2(h01, u2h2(wa.x), a0, false);
      a0 = __builtin_amdgcn_fdot2(h23, u2h2(wb.x), a0, false);
      a1 = __builtin_amdgcn_fdot2(h01, u2h2(wa.y), a1, false);
      a1 = __builtin_amdgcn_fdot2(h23, u2h2(wb.y), a1, false);
      a2 = __builtin_amdgcn_fdot2(h01, u2h2(wa.z), a2, false);
      a2 = __builtin_amdgcn_fdot2(h23, u2h2(wb.z), a2, false);
      a3 = __builtin_amdgcn_fdot2(h01, u2h2(wa.w), a3, false);
      a3 = __builtin_amdgcn_fdot2(h23, u2h2(wb.w), a3, false);
    }
    a0 += __shfl_xor(a0,16,64); a0 += __shfl_xor(a0,32,64);
    a1 += __shfl_xor(a1,16,64); a1 += __shfl_xor(a1,32,64);
    a2 += __shfl_xor(a2,16,64); a2 += __shfl_xor(a2,32,64);
    a3 += __shfl_xor(a3,16,64); a3 += __shfl_xor(a3,32,64);
    if(l<15){
      cs[w*60 + l*4 + 0] = a0;
      cs[w*60 + l*4 + 1] = a1;
      cs[w*60 + l*4 + 2] = a2;
      cs[w*60 + l*4 + 3] = a3;
    }
  }
  __syncthreads();
  if(t<NC){
    float v = cs[t]+cs[60+t]+cs[120+t]+cs[180+t] + bc[t];
    stout(out, bid*NC+t, isbf, v);
  }
}

__global__ void k4_pred(const void* bm, const int* flagp, void* out){
  int b = blockIdx.x, t = threadIdx.x;
  int isbf = flagp[0];
  if(t<NC){
    float acc=0.f;
    for(int r=0;r<90;r++) acc += ldin(bm, (b*90+r)*NC+t, isbf);
    stout(out, NROW*NC + b*NC + t, isbf, acc*(1.f/90.f));
  }
}

extern "C" void kernel_launch(void* const* d_in, const int* in_sizes, int n_in,
                              void* d_out, int out_size, void* d_ws, size_t ws_size,
                              hipStream_t stream){
  const void* x   = d_in[0];
  const void* adj = d_in[1];
  char* ws = (char*)d_ws;
  int*     flagp = (int*)ws;
  float*   M     = (float*)(ws + WS_M_OFF);
  float*   pw    = (float*)(ws + WS_PW_OFF);
  half_t*  W3bf  = (half_t*)(ws + WS_W3BF_OFF);
  half_t*  W2bf  = (half_t*)(ws + WS_W2BF_OFF);
  half_t*  W1bf  = (half_t*)(ws + WS_W1BF_OFF);
  half_t*  Wcp4  = (half_t*)(ws + WS_WCP_OFF);
  half_t*  Wcpf  = (half_t*)(ws + WS_WCPF_OFF);
  float*   part  = (float*)(ws + WS_PART_OFF);
  half_t*  gH3   = (half_t*)(ws + WS_GH3_OFF);
  bool fast = (ws_size >= WS_NEED);

  if(fast){
    k_prep<<<PREP_K1B+1,256,0,stream>>>(d_in[2],d_in[3],d_in[4],d_in[5],
                                        d_in[6],d_in[7],d_in[8],d_in[9],
                                        d_in[10],d_in[11],d_in[12],d_in[13],
                                        d_in[15], x, adj,
                                        flagp, pw, M, W3bf, W2bf, W1bf);
    k3_fast<<<NROW+NFOLDB,256,0,stream>>>(x, pw, W3bf, W2bf, W1bf,
                                          M, d_in[14], Wcpf, flagp, (uint32*)gH3);
    dim3 g5(45,8);
    k5_gemm<<<g5,256,0,stream>>>(gH3, Wcpf, part);
    k6_out<<<BB,256,0,stream>>>(part, pw, flagp, d_out);
  } else {
    k0_prep<<<1,256,0,stream>>>(x, adj, flagp, M);
    k1_all<<<(R_W1E+255)/256,256,0,stream>>>(d_in[2],d_in[3],d_in[4],d_in[5],
                                             d_in[6],d_in[7],d_in[8],d_in[9],
                                             d_in[10],d_in[11],d_in[12],d_in[13],
                                             d_in[15], flagp, pw, W3bf, W2bf, W1bf);
    k2_fold<<<1500,256,0,stream>>>(d_in[14], M, flagp, Wcp4);
    k3_fused<<<NROW,256,0,stream>>>(x, pw, W3bf, W2bf, W1bf,
                                    (const unsigned short*)Wcp4, flagp, d_out);
    k4_pred<<<BB,64,0,stream>>>(d_out, flagp, d_out);
  }
}